// Round 4
// baseline (1281.631 us; speedup 1.0000x reference)
//
#include <hip/hip_runtime.h>

#define PPX  128
#define PP2  16384          // PPX*PPX
#define IMH  896
#define IMW  896
#define NB   24
#define NI   8
#define HP   1152           // IMH + 256 (padded)
#define WP   1152
#define NBI  32             // blocks per image chain
#define NSPARE 8
#define GRIDB (NI*NBI + NSPARE)   // 264

// ws layout (float units):
// [0..5]                     mu_p[3], sd_p[3]
// [8 .. 8+192*8)             per-box structs (8 floats each)
// [2048 .. 2048+192*512)     mask bitmaps (uint32 words, 512 per box)
// [100352 .. 100352+8*32*6)  per-(image,block) partial stats
// [101888 .. +16)            barrier counters (uint32): [0]=grid, [1..8]=per-image
// [102400 .. +8*PP2*3)       patch_bg buffers per image
#define WS_BOX  8
#define WS_MASK 2048
#define WS_PART 100352
#define WS_CNT  101888
#define WS_PBG  102400

// monotonic-counter barrier among a fixed peer group (uniform control flow).
__device__ __forceinline__ void sync_peer(unsigned* cnt, unsigned target) {
  __syncthreads();
  if (threadIdx.x == 0) {
    __threadfence();                               // release
    atomicAdd(cnt, 1u);                            // device-scope RMW
    while (__atomic_load_n(cnt, __ATOMIC_RELAXED) < target)
      __builtin_amdgcn_s_sleep(1);
    __threadfence();                               // acquire
  }
  __syncthreads();
}

__global__ __launch_bounds__(256) void persist_k(
    float* __restrict__ out, const float* __restrict__ images,
    const float* __restrict__ patch, const float* __restrict__ boxes,
    const float* __restrict__ Wsc, const float* __restrict__ bsc,
    const float* __restrict__ Wg, const float* __restrict__ bgv,
    float* __restrict__ ws)
{
  const int bid = blockIdx.x, tid = threadIdx.x;
  unsigned* cnts = (unsigned*)(ws + WS_CNT);

  __shared__ float s_red6[256][6];     // patch_stats / reused scratch
  __shared__ float s_ab[6];
  __shared__ unsigned s_mask[512];

  // ---------- phase 0: copy images -> out (all blocks, grid-stride) ----------
  {
    const float4* src = (const float4*)images;
    float4* dst = (float4*)out;
    const int n4 = NI*IMH*IMW*3/4;
    for (int i = bid*256 + tid; i < n4; i += GRIDB*256) dst[i] = src[i];
  }

  // ---------- phase 0b: per-box setup (blocks 0..191), patch stats (block 256) ----------
  if (bid < NI*NB) {
    const int bn = bid;
    const float* bx = boxes + bn*4;
    float ya = bx[0], xa = bx[1], yb = bx[2], xb = bx[3];
    float bh = (yb - ya) / (float)IMH;
    float bw = (xb - xa) / (float)IMW;
    float z  = bh*Wsc[0] + bw*Wsc[1] + bsc[0];
    float sig = 1.0f / (1.0f + expf(-z));
    float scale = sig * 0.4f;
    float h = yb - ya, w = xb - xa;
    float ps = floorf(sqrtf((h*w)*scale));
    float oy = ya + h*0.5f, ox = xa + w*0.5f;
    float ymp = fmaxf(oy - ps*0.5f, 0.0f);
    float xmp = fmaxf(ox - ps*0.5f, 0.0f);
    if (ymp + ps > (float)IMH) ymp = (float)IMH - ps;
    if (xmp + ps > (float)IMW) xmp = (float)IMW - ps;
    int yi = (int)ymp, xi = (int)xmp, ph = (int)ps;
    float valid = (ps > 60.0f) ? 1.0f : 0.0f;

    unsigned int* mwords = ((unsigned int*)ws) + WS_MASK + bn*512;
    float lsum = 0.f;
    int lane = tid & 63;
    for (int i = 0; i < 64; ++i) {
      int p = i*256 + tid;
      float zz = bh*Wg[p] + bw*Wg[PP2 + p] + bgv[p];
      lsum += 1.0f / (1.0f + expf(-zz));
      unsigned long long m = __ballot(zz > 0.0f);
      if (lane == 0) {
        int base = p >> 5;
        mwords[base]   = (unsigned int)(m & 0xffffffffULL);
        mwords[base+1] = (unsigned int)(m >> 32);
      }
    }
    s_red6[tid][0] = lsum;
    __syncthreads();
    for (int s = 128; s > 0; s >>= 1) {
      if (tid < s) s_red6[tid][0] += s_red6[tid + s][0];
      __syncthreads();
    }
    if (tid == 0) {
      float* bst = ws + WS_BOX + bn*8;
      bst[0] = scale;
      bst[1] = ps;
      ((int*)bst)[2] = yi;
      ((int*)bst)[3] = xi;
      ((int*)bst)[4] = ph;
      bst[5] = valid;
      bst[6] = s_red6[0][0] * (1.0f/PP2);
      bst[7] = 0.f;
    }
  } else if (bid == NI*NBI) {
    // patch stats
    float s0=0,s1=0,s2=0,q0=0,q1=0,q2=0;
    for (int i = tid; i < PP2; i += 256) {
      float a = patch[i*3+0], b = patch[i*3+1], c = patch[i*3+2];
      s0+=a; s1+=b; s2+=c; q0+=a*a; q1+=b*b; q2+=c*c;
    }
    s_red6[tid][0]=s0; s_red6[tid][1]=s1; s_red6[tid][2]=s2;
    s_red6[tid][3]=q0; s_red6[tid][4]=q1; s_red6[tid][5]=q2;
    __syncthreads();
    for (int s = 128; s > 0; s >>= 1) {
      if (tid < s)
        for (int k=0;k<6;++k) s_red6[tid][k] += s_red6[tid+s][k];
      __syncthreads();
    }
    if (tid == 0) {
      for (int c=0;c<3;++c) {
        float mu  = s_red6[0][c]   * (1.0f/PP2);
        float var = s_red6[0][3+c] * (1.0f/PP2) - mu*mu;
        float sd  = sqrtf(fmaxf(var, 0.f)) + 1e-6f;
        ws[c] = mu; ws[3+c] = sd;
      }
    }
  }

  // ---------- grid-wide barrier: copy + setup visible everywhere ----------
  sync_peer(&cnts[0], GRIDB);

  if (bid >= NI*NBI) {
    // spare blocks: one computes the scalar loss, rest exit.
    if (bid == NI*NBI + 1 && tid == 0) {
      float total = 0.f;
      for (int b = 0; b < NI; ++b) {
        float sum_s = 0.f, cnt = 0.f, bgl = 0.f;
        for (int n = 0; n < NB; ++n) {
          const float* bst = ws + WS_BOX + (b*NB + n)*8;
          float v = bst[5];
          sum_s += bst[0]*v; cnt += v; bgl += bst[6]*v;
        }
        float nn = fmaxf(cnt, 1.0f);
        float m = sum_s / nn;
        float var = 0.f;
        for (int n = 0; n < NB; ++n) {
          const float* bst = ws + WS_BOX + (b*NB + n)*8;
          float d = bst[0] - m;
          var += bst[5]*d*d;
        }
        var /= nn;
        total += bgl + m + 0.5f*var;
      }
      out[(size_t)NI*IMH*IMW*3] = total;
    }
    return;
  }

  // ---------- per-image chains ----------
  const int b = bid >> 5, blk = bid & (NBI-1);
  unsigned* cimg = &cnts[1 + b];
  unsigned bars = 0;
  float* __restrict__ img = out + (size_t)b*IMH*IMW*3;
  float* __restrict__ pbg = ws + WS_PBG + (size_t)b*PP2*3;

  for (int n = 0; n < NB; ++n) {
    const float* bst = ws + WS_BOX + (b*NB + n)*8;
    if (bst[5] < 0.5f) continue;          // uniform across the image's 32 blocks
    const int yi = ((const int*)bst)[2];
    const int xi = ((const int*)bst)[3];
    const int ph = ((const int*)bst)[4];
    const float phf = (float)(ph > 1 ? ph : 1);

    // ---- crop: this block's 512 of 16384 pixels + partial stats ----
    {
      float sm[3] = {0,0,0}, sq[3] = {0,0,0};
      #pragma unroll
      for (int k = 0; k < 2; ++k) {
        int idx = blk*512 + k*256 + tid;
        int py = idx >> 7, px = idx & 127;
        float ys = ((float)yi + (py + 0.5f)*phf*(1.0f/PPX)) - 0.5f;
        float xs = ((float)xi + (px + 0.5f)*phf*(1.0f/PPX)) - 0.5f;
        ys = fminf(fmaxf(ys, 0.f), (float)(HP-1));
        xs = fminf(fmaxf(xs, 0.f), (float)(WP-1));
        float fy0 = floorf(ys), fx0 = floorf(xs);
        int y0 = (int)fy0, x0 = (int)fx0;
        int y1 = y0 + 1 < HP-1 ? y0 + 1 : HP-1;
        int x1 = x0 + 1 < WP-1 ? x0 + 1 : WP-1;
        float wy = ys - fy0, wx = xs - fx0;
        bool y0i = y0 < IMH, y1i = y1 < IMH, x0i = x0 < IMW, x1i = x1 < IMW;
        const float* r0 = img + (size_t)y0*IMW*3;
        const float* r1 = img + (size_t)y1*IMW*3;
        #pragma unroll
        for (int c = 0; c < 3; ++c) {
          float v00 = (y0i && x0i) ? r0[x0*3+c] : 0.f;
          float v01 = (y0i && x1i) ? r0[x1*3+c] : 0.f;
          float v10 = (y1i && x0i) ? r1[x0*3+c] : 0.f;
          float v11 = (y1i && x1i) ? r1[x1*3+c] : 0.f;
          float v = (1.f-wy)*((1.f-wx)*v00 + wx*v01) + wy*((1.f-wx)*v10 + wx*v11);
          pbg[idx*3+c] = v;
          sm[c] += v; sq[c] += v*v;
        }
      }
      float vals[6] = {sm[0],sm[1],sm[2],sq[0],sq[1],sq[2]};
      #pragma unroll
      for (int off = 32; off; off >>= 1)
        #pragma unroll
        for (int k = 0; k < 6; ++k) vals[k] += __shfl_down(vals[k], off);
      int wid = tid >> 6;
      if ((tid & 63) == 0)
        for (int k = 0; k < 6; ++k) s_red6[wid][k] = vals[k];
      __syncthreads();
      if (tid == 0) {
        float* part = ws + WS_PART + (b*NBI + blk)*6;
        for (int k = 0; k < 6; ++k)
          part[k] = s_red6[0][k] + s_red6[1][k] + s_red6[2][k] + s_red6[3][k];
      }
    }
    sync_peer(cimg, NBI * (++bars));

    // ---- paste: reduce stats, blend+resize into ph x ph region ----
    {
      const unsigned int* mwords = ((const unsigned int*)ws) + WS_MASK + (b*NB + n)*512;
      s_mask[tid]       = mwords[tid];
      s_mask[tid + 256] = mwords[tid + 256];
      if (tid < 32) {
        const float* part = ws + WS_PART + (b*NBI + tid)*6;
        float v[6];
        #pragma unroll
        for (int k = 0; k < 6; ++k) v[k] = part[k];
        #pragma unroll
        for (int off = 16; off; off >>= 1)
          #pragma unroll
          for (int k = 0; k < 6; ++k) v[k] += __shfl_down(v[k], off, 32);
        if (tid == 0) {
          #pragma unroll
          for (int c = 0; c < 3; ++c) {
            float mu  = v[c]   * (1.0f/PP2);
            float var = v[3+c] * (1.0f/PP2) - mu*mu;
            float sd  = sqrtf(fmaxf(var, 0.f)) + 1e-6f;
            float alpha = sd / ws[3+c];
            s_ab[c]   = alpha;
            s_ab[3+c] = mu - ws[c]*alpha;
          }
        }
      }
      __syncthreads();

      const int tot = ph*ph;
      const int chunk = (tot + NBI - 1) / NBI;
      const int i0 = blk*chunk;
      const int i1 = min(tot, i0 + chunk);
      for (int idx = i0 + tid; idx < i1; idx += 256) {
        int r = (int)((unsigned)idx / (unsigned)ph);
        int c = idx - r*ph;
        float sy = ((r + 0.5f)*128.0f)/phf - 0.5f;
        float sx = ((c + 0.5f)*128.0f)/phf - 0.5f;
        sy = fminf(fmaxf(sy, 0.f), 127.f);
        sx = fminf(fmaxf(sx, 0.f), 127.f);
        float fy0 = floorf(sy), fx0 = floorf(sx);
        int py0 = (int)fy0, px0 = (int)fx0;
        int py1 = py0 + 1 < 127 ? py0 + 1 : 127;
        int px1 = px0 + 1 < 127 ? px0 + 1 : 127;
        float wy = sy - fy0, wx = sx - fx0;
        int i00 = (py0<<7)+px0, i01 = (py0<<7)+px1, i10 = (py1<<7)+px0, i11 = (py1<<7)+px1;
        bool m00 = (s_mask[i00>>5] >> (i00&31)) & 1u;
        bool m01 = (s_mask[i01>>5] >> (i01&31)) & 1u;
        bool m10 = (s_mask[i10>>5] >> (i10&31)) & 1u;
        bool m11 = (s_mask[i11>>5] >> (i11&31)) & 1u;
        float* dst = img + ((size_t)(yi + r)*IMW + (xi + c))*3;
        #pragma unroll
        for (int ch = 0; ch < 3; ++ch) {
          float a = s_ab[ch], be = s_ab[3+ch];
          float t00 = m00 ? patch[i00*3+ch]*a + be : pbg[i00*3+ch];
          float t01 = m01 ? patch[i01*3+ch]*a + be : pbg[i01*3+ch];
          float t10 = m10 ? patch[i10*3+ch]*a + be : pbg[i10*3+ch];
          float t11 = m11 ? patch[i11*3+ch]*a + be : pbg[i11*3+ch];
          float v = (1.f-wy)*((1.f-wx)*t00 + wx*t01) + wy*((1.f-wx)*t10 + wx*t11);
          dst[ch] = v;
        }
      }
    }
    sync_peer(cimg, NBI * (++bars));
  }
}

extern "C" void kernel_launch(void* const* d_in, const int* in_sizes, int n_in,
                              void* d_out, int out_size, void* d_ws, size_t ws_size,
                              hipStream_t stream) {
  const float* boxes  = (const float*)d_in[0];
  const float* images = (const float*)d_in[1];
  const float* patch  = (const float*)d_in[2];
  const float* Wsc    = (const float*)d_in[3];
  const float* bsc    = (const float*)d_in[4];
  const float* Wg     = (const float*)d_in[5];
  const float* bgv    = (const float*)d_in[6];
  float* out = (float*)d_out;
  float* ws  = (float*)d_ws;

  // zero the barrier counters (deterministic across graph replays)
  (void)hipMemsetAsync((char*)d_ws + (size_t)WS_CNT*4, 0, 64, stream);

  void* args[] = {&out, &images, &patch, &boxes, &Wsc, &bsc, &Wg, &bgv, &ws};
  (void)hipLaunchCooperativeKernel((void*)persist_k, dim3(GRIDB), dim3(256), args, 0, stream);
}

// Round 5
// 782.393 us; speedup vs baseline: 1.6381x; 1.6381x over previous
//
#include <hip/hip_runtime.h>

#define PPX  128
#define PP2  16384          // PPX*PPX
#define IMH  896
#define IMW  896
#define NB   24
#define NI   8
#define HP   1152           // IMH + 256 (padded)
#define WP   1152
#define NBI  32             // blocks per image chain
#define NSPARE 8
#define GRIDB (NI*NBI + NSPARE)   // 264

// ws layout (float units):
// [0..5]                     mu_p[3], sd_p[3]
// [8 .. 8+192*8)             per-box structs (8 floats each)
// [2048 .. 2048+192*512)     mask bitmaps (uint32 words, 512 per box)
// [100352 .. 100352+8*32*6)  per-(image,block) partial stats
// [101888 .. +9*32)          barrier counters (uint32), one 128B line each:
//                            [0]=grid, [(1+b)*32]=image b
// [102400 .. +8*PP2*3)       patch_bg buffers per image
#define WS_BOX  8
#define WS_MASK 2048
#define WS_PART 100352
#define WS_CNT  101888
#define WS_PBG  102400

__global__ void copy_img_k(const float4* __restrict__ src, float4* __restrict__ dst, int n4) {
  int i = blockIdx.x * blockDim.x + threadIdx.x;
  int stride = gridDim.x * blockDim.x;
  for (; i < n4; i += stride) dst[i] = src[i];
}

// monotonic-counter barrier among a fixed peer group (uniform control flow).
// Poll via RMW: always served at the device coherence point (never stale).
__device__ __forceinline__ void sync_peer(unsigned* cnt, unsigned target) {
  __syncthreads();
  if (threadIdx.x == 0) {
    __threadfence();                               // release
    atomicAdd(cnt, 1u);
    while (atomicAdd(cnt, 0u) < target)
      __builtin_amdgcn_s_sleep(2);
    __threadfence();                               // acquire
  }
  __syncthreads();
}

__global__ __launch_bounds__(256) void persist_k(
    float* __restrict__ out, const float* __restrict__ patch,
    const float* __restrict__ boxes,
    const float* __restrict__ Wsc, const float* __restrict__ bsc,
    const float* __restrict__ Wg, const float* __restrict__ bgv,
    float* __restrict__ ws)
{
  const int bid = blockIdx.x, tid = threadIdx.x;
  unsigned* cnts = (unsigned*)(ws + WS_CNT);

  __shared__ float s_red6[256][6];     // patch_stats / reused scratch
  __shared__ float s_ab[6];
  __shared__ unsigned s_mask[512];

  // ---------- phase 0: per-box setup (blocks 0..191), patch stats (block 256) ----------
  if (bid < NI*NB) {
    const int bn = bid;
    const float* bx = boxes + bn*4;
    float ya = bx[0], xa = bx[1], yb = bx[2], xb = bx[3];
    float bh = (yb - ya) / (float)IMH;
    float bw = (xb - xa) / (float)IMW;
    float z  = bh*Wsc[0] + bw*Wsc[1] + bsc[0];
    float sig = 1.0f / (1.0f + expf(-z));
    float scale = sig * 0.4f;
    float h = yb - ya, w = xb - xa;
    float ps = floorf(sqrtf((h*w)*scale));
    float oy = ya + h*0.5f, ox = xa + w*0.5f;
    float ymp = fmaxf(oy - ps*0.5f, 0.0f);
    float xmp = fmaxf(ox - ps*0.5f, 0.0f);
    if (ymp + ps > (float)IMH) ymp = (float)IMH - ps;
    if (xmp + ps > (float)IMW) xmp = (float)IMW - ps;
    int yi = (int)ymp, xi = (int)xmp, ph = (int)ps;
    float valid = (ps > 60.0f) ? 1.0f : 0.0f;

    unsigned int* mwords = ((unsigned int*)ws) + WS_MASK + bn*512;
    float lsum = 0.f;
    int lane = tid & 63;
    for (int i = 0; i < 64; ++i) {
      int p = i*256 + tid;
      float zz = bh*Wg[p] + bw*Wg[PP2 + p] + bgv[p];
      lsum += 1.0f / (1.0f + expf(-zz));
      unsigned long long m = __ballot(zz > 0.0f);
      if (lane == 0) {
        int base = p >> 5;
        mwords[base]   = (unsigned int)(m & 0xffffffffULL);
        mwords[base+1] = (unsigned int)(m >> 32);
      }
    }
    s_red6[tid][0] = lsum;
    __syncthreads();
    for (int s = 128; s > 0; s >>= 1) {
      if (tid < s) s_red6[tid][0] += s_red6[tid + s][0];
      __syncthreads();
    }
    if (tid == 0) {
      float* bst = ws + WS_BOX + bn*8;
      bst[0] = scale;
      bst[1] = ps;
      ((int*)bst)[2] = yi;
      ((int*)bst)[3] = xi;
      ((int*)bst)[4] = ph;
      bst[5] = valid;
      bst[6] = s_red6[0][0] * (1.0f/PP2);
      bst[7] = 0.f;
    }
  } else if (bid == NI*NBI) {
    // patch stats
    float s0=0,s1=0,s2=0,q0=0,q1=0,q2=0;
    for (int i = tid; i < PP2; i += 256) {
      float a = patch[i*3+0], b = patch[i*3+1], c = patch[i*3+2];
      s0+=a; s1+=b; s2+=c; q0+=a*a; q1+=b*b; q2+=c*c;
    }
    s_red6[tid][0]=s0; s_red6[tid][1]=s1; s_red6[tid][2]=s2;
    s_red6[tid][3]=q0; s_red6[tid][4]=q1; s_red6[tid][5]=q2;
    __syncthreads();
    for (int s = 128; s > 0; s >>= 1) {
      if (tid < s)
        for (int k=0;k<6;++k) s_red6[tid][k] += s_red6[tid+s][k];
      __syncthreads();
    }
    if (tid == 0) {
      for (int c=0;c<3;++c) {
        float mu  = s_red6[0][c]   * (1.0f/PP2);
        float var = s_red6[0][3+c] * (1.0f/PP2) - mu*mu;
        float sd  = sqrtf(fmaxf(var, 0.f)) + 1e-6f;
        ws[c] = mu; ws[3+c] = sd;
      }
    }
  }

  // ---------- grid-wide barrier: setup visible everywhere ----------
  sync_peer(&cnts[0], GRIDB);

  if (bid >= NI*NBI) {
    // spare blocks: one computes the scalar loss, rest exit.
    if (bid == NI*NBI + 1 && tid == 0) {
      float total = 0.f;
      for (int b = 0; b < NI; ++b) {
        float sum_s = 0.f, cnt = 0.f, bgl = 0.f;
        for (int n = 0; n < NB; ++n) {
          const float* bst = ws + WS_BOX + (b*NB + n)*8;
          float v = bst[5];
          sum_s += bst[0]*v; cnt += v; bgl += bst[6]*v;
        }
        float nn = fmaxf(cnt, 1.0f);
        float m = sum_s / nn;
        float var = 0.f;
        for (int n = 0; n < NB; ++n) {
          const float* bst = ws + WS_BOX + (b*NB + n)*8;
          float d = bst[0] - m;
          var += bst[5]*d*d;
        }
        var /= nn;
        total += bgl + m + 0.5f*var;
      }
      out[(size_t)NI*IMH*IMW*3] = total;
    }
    return;
  }

  // ---------- per-image chains ----------
  const int b = bid >> 5, blk = bid & (NBI-1);
  unsigned* cimg = cnts + (1 + b)*32;
  unsigned bars = 0;
  float* __restrict__ img = out + (size_t)b*IMH*IMW*3;
  float* __restrict__ pbg = ws + WS_PBG + (size_t)b*PP2*3;

  for (int n = 0; n < NB; ++n) {
    const float* bst = ws + WS_BOX + (b*NB + n)*8;
    if (bst[5] < 0.5f) continue;          // uniform across the image's 32 blocks
    const int yi = ((const int*)bst)[2];
    const int xi = ((const int*)bst)[3];
    const int ph = ((const int*)bst)[4];
    const float phf = (float)(ph > 1 ? ph : 1);

    // ---- crop: this block's 512 of 16384 pixels + partial stats ----
    {
      float sm[3] = {0,0,0}, sq[3] = {0,0,0};
      #pragma unroll
      for (int k = 0; k < 2; ++k) {
        int idx = blk*512 + k*256 + tid;
        int py = idx >> 7, px = idx & 127;
        float ys = ((float)yi + (py + 0.5f)*phf*(1.0f/PPX)) - 0.5f;
        float xs = ((float)xi + (px + 0.5f)*phf*(1.0f/PPX)) - 0.5f;
        ys = fminf(fmaxf(ys, 0.f), (float)(HP-1));
        xs = fminf(fmaxf(xs, 0.f), (float)(WP-1));
        float fy0 = floorf(ys), fx0 = floorf(xs);
        int y0 = (int)fy0, x0 = (int)fx0;
        int y1 = y0 + 1 < HP-1 ? y0 + 1 : HP-1;
        int x1 = x0 + 1 < WP-1 ? x0 + 1 : WP-1;
        float wy = ys - fy0, wx = xs - fx0;
        bool y0i = y0 < IMH, y1i = y1 < IMH, x0i = x0 < IMW, x1i = x1 < IMW;
        const float* r0 = img + (size_t)y0*IMW*3;
        const float* r1 = img + (size_t)y1*IMW*3;
        #pragma unroll
        for (int c = 0; c < 3; ++c) {
          float v00 = (y0i && x0i) ? r0[x0*3+c] : 0.f;
          float v01 = (y0i && x1i) ? r0[x1*3+c] : 0.f;
          float v10 = (y1i && x0i) ? r1[x0*3+c] : 0.f;
          float v11 = (y1i && x1i) ? r1[x1*3+c] : 0.f;
          float v = (1.f-wy)*((1.f-wx)*v00 + wx*v01) + wy*((1.f-wx)*v10 + wx*v11);
          pbg[idx*3+c] = v;
          sm[c] += v; sq[c] += v*v;
        }
      }
      float vals[6] = {sm[0],sm[1],sm[2],sq[0],sq[1],sq[2]};
      #pragma unroll
      for (int off = 32; off; off >>= 1)
        #pragma unroll
        for (int k = 0; k < 6; ++k) vals[k] += __shfl_down(vals[k], off);
      int wid = tid >> 6;
      if ((tid & 63) == 0)
        for (int k = 0; k < 6; ++k) s_red6[wid][k] = vals[k];
      __syncthreads();
      if (tid == 0) {
        float* part = ws + WS_PART + (b*NBI + blk)*6;
        for (int k = 0; k < 6; ++k)
          part[k] = s_red6[0][k] + s_red6[1][k] + s_red6[2][k] + s_red6[3][k];
      }
    }
    sync_peer(cimg, NBI * (++bars));

    // ---- paste: reduce stats, blend+resize into ph x ph region ----
    {
      const unsigned int* mwords = ((const unsigned int*)ws) + WS_MASK + (b*NB + n)*512;
      s_mask[tid]       = mwords[tid];
      s_mask[tid + 256] = mwords[tid + 256];
      if (tid < 32) {
        const float* part = ws + WS_PART + (b*NBI + tid)*6;
        float v[6];
        #pragma unroll
        for (int k = 0; k < 6; ++k) v[k] = part[k];
        #pragma unroll
        for (int off = 16; off; off >>= 1)
          #pragma unroll
          for (int k = 0; k < 6; ++k) v[k] += __shfl_down(v[k], off, 32);
        if (tid == 0) {
          #pragma unroll
          for (int c = 0; c < 3; ++c) {
            float mu  = v[c]   * (1.0f/PP2);
            float var = v[3+c] * (1.0f/PP2) - mu*mu;
            float sd  = sqrtf(fmaxf(var, 0.f)) + 1e-6f;
            float alpha = sd / ws[3+c];
            s_ab[c]   = alpha;
            s_ab[3+c] = mu - ws[c]*alpha;
          }
        }
      }
      __syncthreads();

      const int tot = ph*ph;
      const int chunk = (tot + NBI - 1) / NBI;
      const int i0 = blk*chunk;
      const int i1 = min(tot, i0 + chunk);
      for (int idx = i0 + tid; idx < i1; idx += 256) {
        int r = (int)((unsigned)idx / (unsigned)ph);
        int c = idx - r*ph;
        float sy = ((r + 0.5f)*128.0f)/phf - 0.5f;
        float sx = ((c + 0.5f)*128.0f)/phf - 0.5f;
        sy = fminf(fmaxf(sy, 0.f), 127.f);
        sx = fminf(fmaxf(sx, 0.f), 127.f);
        float fy0 = floorf(sy), fx0 = floorf(sx);
        int py0 = (int)fy0, px0 = (int)fx0;
        int py1 = py0 + 1 < 127 ? py0 + 1 : 127;
        int px1 = px0 + 1 < 127 ? px0 + 1 : 127;
        float wy = sy - fy0, wx = sx - fx0;
        int i00 = (py0<<7)+px0, i01 = (py0<<7)+px1, i10 = (py1<<7)+px0, i11 = (py1<<7)+px1;
        bool m00 = (s_mask[i00>>5] >> (i00&31)) & 1u;
        bool m01 = (s_mask[i01>>5] >> (i01&31)) & 1u;
        bool m10 = (s_mask[i10>>5] >> (i10&31)) & 1u;
        bool m11 = (s_mask[i11>>5] >> (i11&31)) & 1u;
        float* dst = img + ((size_t)(yi + r)*IMW + (xi + c))*3;
        #pragma unroll
        for (int ch = 0; ch < 3; ++ch) {
          float a = s_ab[ch], be = s_ab[3+ch];
          float t00 = m00 ? patch[i00*3+ch]*a + be : pbg[i00*3+ch];
          float t01 = m01 ? patch[i01*3+ch]*a + be : pbg[i01*3+ch];
          float t10 = m10 ? patch[i10*3+ch]*a + be : pbg[i10*3+ch];
          float t11 = m11 ? patch[i11*3+ch]*a + be : pbg[i11*3+ch];
          float v = (1.f-wy)*((1.f-wx)*t00 + wx*t01) + wy*((1.f-wx)*t10 + wx*t11);
          dst[ch] = v;
        }
      }
    }
    sync_peer(cimg, NBI * (++bars));
  }
}

extern "C" void kernel_launch(void* const* d_in, const int* in_sizes, int n_in,
                              void* d_out, int out_size, void* d_ws, size_t ws_size,
                              hipStream_t stream) {
  const float* boxes  = (const float*)d_in[0];
  const float* images = (const float*)d_in[1];
  const float* patch  = (const float*)d_in[2];
  const float* Wsc    = (const float*)d_in[3];
  const float* bsc    = (const float*)d_in[4];
  const float* Wg     = (const float*)d_in[5];
  const float* bgv    = (const float*)d_in[6];
  float* out = (float*)d_out;
  float* ws  = (float*)d_ws;

  // zero the padded barrier counters (deterministic across graph replays)
  (void)hipMemsetAsync((char*)d_ws + (size_t)WS_CNT*4, 0, 9*32*4, stream);

  // full-grid copy: 154 MB at ~6-7 TB/s
  int n4 = (NI*IMH*IMW*3) / 4;
  copy_img_k<<<2048, 256, 0, stream>>>((const float4*)images, (float4*)out, n4);

  void* args[] = {&out, &patch, &boxes, &Wsc, &bsc, &Wg, &bgv, &ws};
  (void)hipLaunchCooperativeKernel((void*)persist_k, dim3(GRIDB), dim3(256), args, 0, stream);
}

// Round 6
// 281.002 us; speedup vs baseline: 4.5609x; 2.7843x over previous
//
#include <hip/hip_runtime.h>

#define PPX  128
#define PP2  16384          // PPX*PPX
#define IMH  896
#define IMW  896
#define NB   24
#define NI   8
#define HP   1152           // padded height
#define WP   1152
#define PB   32             // paste blocks per image
#define CB   32             // crop blocks per image
#define SB   (PB+CB)        // 64 blocks per image per step

// ws layout (float units):
// [0..5]                       mu_p[3], sd_p[3]
// [8 .. 8+192*8)               per-box structs
// [2048 .. 2048+192*512)       mask bitmaps (uint32 words)
// [100352 .. +2*8*32*6)        double-buffered per-(image,block) partial stats
// [103424 .. +2*8*PP2*3)       double-buffered patch_bg per image
#define WS_BOX   8
#define WS_MASK  2048
#define WS_PART  100352
#define WS_PBG   103424

// ---- the paste value at region-relative pixel (rr,cc), all 3 channels ----
// bit-identical to the round-2 paste inner loop.
__device__ __forceinline__ void analytic3(
    int rr, int cc, float phf, const float* __restrict__ pbg1,
    const float* __restrict__ patch, const unsigned* __restrict__ msk,
    const float* __restrict__ ab, float v[3])
{
  float sy = ((rr + 0.5f)*128.0f)/phf - 0.5f;
  float sx = ((cc + 0.5f)*128.0f)/phf - 0.5f;
  sy = fminf(fmaxf(sy, 0.f), 127.f);
  sx = fminf(fmaxf(sx, 0.f), 127.f);
  float fy0 = floorf(sy), fx0 = floorf(sx);
  int py0 = (int)fy0, px0 = (int)fx0;
  int py1 = py0 + 1 < 127 ? py0 + 1 : 127;
  int px1 = px0 + 1 < 127 ? px0 + 1 : 127;
  float wy = sy - fy0, wx = sx - fx0;
  int i00 = (py0<<7)+px0, i01 = (py0<<7)+px1, i10 = (py1<<7)+px0, i11 = (py1<<7)+px1;
  bool m00 = (msk[i00>>5] >> (i00&31)) & 1u;
  bool m01 = (msk[i01>>5] >> (i01&31)) & 1u;
  bool m10 = (msk[i10>>5] >> (i10&31)) & 1u;
  bool m11 = (msk[i11>>5] >> (i11&31)) & 1u;
  #pragma unroll
  for (int ch = 0; ch < 3; ++ch) {
    float a = ab[ch], be = ab[3+ch];
    float t00 = m00 ? patch[i00*3+ch]*a + be : pbg1[i00*3+ch];
    float t01 = m01 ? patch[i01*3+ch]*a + be : pbg1[i01*3+ch];
    float t10 = m10 ? patch[i10*3+ch]*a + be : pbg1[i10*3+ch];
    float t11 = m11 ? patch[i11*3+ch]*a + be : pbg1[i11*3+ch];
    v[ch] = (1.f-wy)*((1.f-wx)*t00 + wx*t01) + wy*((1.f-wx)*t10 + wx*t11);
  }
}

// corner fetch: zero-pad outside image; analytic inside previous box's region.
__device__ __forceinline__ void fetch_corner(
    const float* __restrict__ src, int Y, int X, bool hasp,
    int yi1, int xi1, int ph1, float phf1,
    const float* __restrict__ pbg1, const float* __restrict__ patch,
    const unsigned* __restrict__ msk, const float* __restrict__ ab, float v[3])
{
  if (Y >= IMH || X >= IMW) { v[0]=0.f; v[1]=0.f; v[2]=0.f; return; }
  if (hasp && (unsigned)(Y - yi1) < (unsigned)ph1
           && (unsigned)(X - xi1) < (unsigned)ph1) {
    analytic3(Y - yi1, X - xi1, phf1, pbg1, patch, msk, ab, v);
    return;
  }
  const float* p = src + ((size_t)Y*IMW + X)*3;
  v[0]=p[0]; v[1]=p[1]; v[2]=p[2];
}

// crop box n of image b: this block's 512 of 16384 pixels + partial stats.
__device__ __forceinline__ void do_crop(
    const float* __restrict__ src, const float* __restrict__ patch,
    float* __restrict__ ws, int b, int blk, int n, bool hasp,
    int yi1, int xi1, int ph1, float phf1,
    const float* __restrict__ pbg1,
    const unsigned* __restrict__ s_mask, const float* __restrict__ s_ab,
    float (*s_red)[6])
{
  const int tid = threadIdx.x;
  const float* bst = ws + WS_BOX + (b*NB + n)*8;
  const int yi = ((const int*)bst)[2];
  const int xi = ((const int*)bst)[3];
  const int ph = ((const int*)bst)[4];
  const float phf = (float)(ph > 1 ? ph : 1);
  float* __restrict__ pbg = ws + WS_PBG + (size_t)((n&1)*NI + b)*PP2*3;

  float sm[3] = {0,0,0}, sq[3] = {0,0,0};
  #pragma unroll
  for (int k = 0; k < 2; ++k) {
    int idx = blk*512 + k*256 + tid;
    int py = idx >> 7, px = idx & 127;
    float ys = ((float)yi + (py + 0.5f)*phf*(1.0f/PPX)) - 0.5f;
    float xs = ((float)xi + (px + 0.5f)*phf*(1.0f/PPX)) - 0.5f;
    ys = fminf(fmaxf(ys, 0.f), (float)(HP-1));
    xs = fminf(fmaxf(xs, 0.f), (float)(WP-1));
    float fy0 = floorf(ys), fx0 = floorf(xs);
    int y0 = (int)fy0, x0 = (int)fx0;
    int y1 = y0 + 1 < HP-1 ? y0 + 1 : HP-1;
    int x1 = x0 + 1 < WP-1 ? x0 + 1 : WP-1;
    float wy = ys - fy0, wx = xs - fx0;
    float c00[3], c01[3], c10[3], c11[3];
    fetch_corner(src, y0, x0, hasp, yi1, xi1, ph1, phf1, pbg1, patch, s_mask, s_ab, c00);
    fetch_corner(src, y0, x1, hasp, yi1, xi1, ph1, phf1, pbg1, patch, s_mask, s_ab, c01);
    fetch_corner(src, y1, x0, hasp, yi1, xi1, ph1, phf1, pbg1, patch, s_mask, s_ab, c10);
    fetch_corner(src, y1, x1, hasp, yi1, xi1, ph1, phf1, pbg1, patch, s_mask, s_ab, c11);
    #pragma unroll
    for (int c = 0; c < 3; ++c) {
      float v = (1.f-wy)*((1.f-wx)*c00[c] + wx*c01[c]) + wy*((1.f-wx)*c10[c] + wx*c11[c]);
      pbg[idx*3+c] = v;
      sm[c] += v; sq[c] += v*v;
    }
  }
  float vals[6] = {sm[0],sm[1],sm[2],sq[0],sq[1],sq[2]};
  #pragma unroll
  for (int off = 32; off; off >>= 1)
    #pragma unroll
    for (int k = 0; k < 6; ++k) vals[k] += __shfl_down(vals[k], off);
  int wid = tid >> 6;
  if ((tid & 63) == 0)
    for (int k = 0; k < 6; ++k) s_red[wid][k] = vals[k];
  __syncthreads();
  if (tid == 0) {
    float* part = ws + WS_PART + (size_t)((n&1)*NI + b)*CB*6 + blk*6;
    for (int k = 0; k < 6; ++k)
      part[k] = s_red[0][k] + s_red[1][k] + s_red[2][k] + s_red[3][k];
  }
}

// ---------------- setup: per-box geometry + masks (192) + patch stats (1) ----------------
__global__ __launch_bounds__(256) void setup_k(
    const float* __restrict__ boxes,
    const float* __restrict__ Wsc, const float* __restrict__ bsc,
    const float* __restrict__ Wg, const float* __restrict__ bgv,
    const float* __restrict__ patch, float* __restrict__ ws)
{
  const int bid = blockIdx.x, tid = threadIdx.x;
  __shared__ float s_red6[256][6];
  if (bid < NI*NB) {
    const int bn = bid;
    const float* bx = boxes + bn*4;
    float ya = bx[0], xa = bx[1], yb = bx[2], xb = bx[3];
    float bh = (yb - ya) / (float)IMH;
    float bw = (xb - xa) / (float)IMW;
    float z  = bh*Wsc[0] + bw*Wsc[1] + bsc[0];
    float sig = 1.0f / (1.0f + expf(-z));
    float scale = sig * 0.4f;
    float h = yb - ya, w = xb - xa;
    float ps = floorf(sqrtf((h*w)*scale));
    float oy = ya + h*0.5f, ox = xa + w*0.5f;
    float ymp = fmaxf(oy - ps*0.5f, 0.0f);
    float xmp = fmaxf(ox - ps*0.5f, 0.0f);
    if (ymp + ps > (float)IMH) ymp = (float)IMH - ps;
    if (xmp + ps > (float)IMW) xmp = (float)IMW - ps;
    int yi = (int)ymp, xi = (int)xmp, ph = (int)ps;
    float valid = (ps > 60.0f) ? 1.0f : 0.0f;

    unsigned int* mwords = ((unsigned int*)ws) + WS_MASK + bn*512;
    float lsum = 0.f;
    int lane = tid & 63;
    for (int i = 0; i < 64; ++i) {
      int p = i*256 + tid;
      float zz = bh*Wg[p] + bw*Wg[PP2 + p] + bgv[p];
      lsum += 1.0f / (1.0f + expf(-zz));
      unsigned long long m = __ballot(zz > 0.0f);
      if (lane == 0) {
        int base = p >> 5;
        mwords[base]   = (unsigned int)(m & 0xffffffffULL);
        mwords[base+1] = (unsigned int)(m >> 32);
      }
    }
    s_red6[tid][0] = lsum;
    __syncthreads();
    for (int s = 128; s > 0; s >>= 1) {
      if (tid < s) s_red6[tid][0] += s_red6[tid + s][0];
      __syncthreads();
    }
    if (tid == 0) {
      float* bst = ws + WS_BOX + bn*8;
      bst[0] = scale;
      bst[1] = ps;
      ((int*)bst)[2] = yi;
      ((int*)bst)[3] = xi;
      ((int*)bst)[4] = ph;
      bst[5] = valid;
      bst[6] = s_red6[0][0] * (1.0f/PP2);
      bst[7] = 0.f;
    }
  } else {
    // patch stats
    float s0=0,s1=0,s2=0,q0=0,q1=0,q2=0;
    for (int i = tid; i < PP2; i += 256) {
      float a = patch[i*3+0], b = patch[i*3+1], c = patch[i*3+2];
      s0+=a; s1+=b; s2+=c; q0+=a*a; q1+=b*b; q2+=c*c;
    }
    s_red6[tid][0]=s0; s_red6[tid][1]=s1; s_red6[tid][2]=s2;
    s_red6[tid][3]=q0; s_red6[tid][4]=q1; s_red6[tid][5]=q2;
    __syncthreads();
    for (int s = 128; s > 0; s >>= 1) {
      if (tid < s)
        for (int k=0;k<6;++k) s_red6[tid][k] += s_red6[tid+s][k];
      __syncthreads();
    }
    if (tid == 0) {
      for (int c=0;c<3;++c) {
        float mu  = s_red6[0][c]   * (1.0f/PP2);
        float var = s_red6[0][3+c] * (1.0f/PP2) - mu*mu;
        float sd  = sqrtf(fmaxf(var, 0.f)) + 1e-6f;
        ws[c] = mu; ws[3+c] = sd;
      }
    }
  }
}

// ---------------- step0: crop box0 (blocks 0..255) + loss (256) + copy (257..) ----------------
__global__ __launch_bounds__(256) void step0_k(
    float* __restrict__ out, const float* __restrict__ images,
    const float* __restrict__ patch, float* __restrict__ ws)
{
  const int bid = blockIdx.x, tid = threadIdx.x;
  __shared__ float s_red[4][6];
  if (bid < NI*CB) {
    const int b = bid >> 5, blk = bid & (CB-1);
    const float* bst = ws + WS_BOX + (b*NB + 0)*8;
    if (bst[5] < 0.5f) return;
    do_crop(images + (size_t)b*IMH*IMW*3, patch, ws, b, blk, 0,
            false, 0, 0, 0, 1.f, nullptr, nullptr, nullptr, s_red);
    return;
  }
  if (bid == NI*CB) {
    if (tid == 0) {
      float total = 0.f;
      for (int b = 0; b < NI; ++b) {
        float sum_s = 0.f, cnt = 0.f, bgl = 0.f;
        for (int n = 0; n < NB; ++n) {
          const float* bst = ws + WS_BOX + (b*NB + n)*8;
          float v = bst[5];
          sum_s += bst[0]*v; cnt += v; bgl += bst[6]*v;
        }
        float nn = fmaxf(cnt, 1.0f);
        float m = sum_s / nn;
        float var = 0.f;
        for (int n = 0; n < NB; ++n) {
          const float* bst = ws + WS_BOX + (b*NB + n)*8;
          float d = bst[0] - m;
          var += bst[5]*d*d;
        }
        var /= nn;
        total += bgl + m + 0.5f*var;
      }
      out[(size_t)NI*IMH*IMW*3] = total;
    }
    return;
  }
  // copy images -> out
  const float4* src = (const float4*)images;
  float4* dst = (float4*)out;
  const int n4 = NI*IMH*IMW*3/4;
  const int nblk = gridDim.x - (NI*CB + 1);
  for (int i = (bid - NI*CB - 1)*256 + tid; i < n4; i += nblk*256) dst[i] = src[i];
}

// ---------------- step n (1..NB): paste(n-1) [blocks r<PB] || crop(n) [r>=PB] ----------------
__global__ __launch_bounds__(256) void step_k(
    float* __restrict__ out, const float* __restrict__ patch,
    float* __restrict__ ws, int n)
{
  const int bid = blockIdx.x, tid = threadIdx.x;
  const int b = bid / SB, r = bid % SB;
  __shared__ float s_ab[6];
  __shared__ unsigned s_mask[512];
  __shared__ float s_red[4][6];

  const float* bst1 = ws + WS_BOX + (b*NB + (n-1))*8;
  const bool hasp = bst1[5] > 0.5f;
  int yi1 = 0, xi1 = 0, ph1 = 0; float phf1 = 1.f;
  const float* pbg1 = ws + WS_PBG + (size_t)(((n-1)&1)*NI + b)*PP2*3;

  if (hasp) {
    yi1 = ((const int*)bst1)[2];
    xi1 = ((const int*)bst1)[3];
    ph1 = ((const int*)bst1)[4];
    phf1 = (float)(ph1 > 1 ? ph1 : 1);
    const unsigned int* mwords = ((const unsigned int*)ws) + WS_MASK + (b*NB + (n-1))*512;
    s_mask[tid]       = mwords[tid];
    s_mask[tid + 256] = mwords[tid + 256];
    if (tid < 32) {
      const float* part = ws + WS_PART + (size_t)(((n-1)&1)*NI + b)*CB*6 + tid*6;
      float v[6];
      #pragma unroll
      for (int k = 0; k < 6; ++k) v[k] = part[k];
      #pragma unroll
      for (int off = 16; off; off >>= 1)
        #pragma unroll
        for (int k = 0; k < 6; ++k) v[k] += __shfl_down(v[k], off, 32);
      if (tid == 0) {
        #pragma unroll
        for (int c = 0; c < 3; ++c) {
          float mu  = v[c]   * (1.0f/PP2);
          float var = v[3+c] * (1.0f/PP2) - mu*mu;
          float sd  = sqrtf(fmaxf(var, 0.f)) + 1e-6f;
          float alpha = sd / ws[3+c];
          s_ab[c]   = alpha;
          s_ab[3+c] = mu - ws[c]*alpha;
        }
      }
    }
    __syncthreads();
  }

  float* __restrict__ img = out + (size_t)b*IMH*IMW*3;

  if (r < PB) {
    // ---- paste box n-1 ----
    if (!hasp) return;
    const int tot = ph1*ph1;
    const int chunk = (tot + PB - 1) / PB;
    const int i0 = r*chunk;
    const int i1 = min(tot, i0 + chunk);
    for (int idx = i0 + tid; idx < i1; idx += 256) {
      int rr = (int)((unsigned)idx / (unsigned)ph1);
      int cc = idx - rr*ph1;
      float v[3];
      analytic3(rr, cc, phf1, pbg1, patch, s_mask, s_ab, v);
      float* dst = img + ((size_t)(yi1 + rr)*IMW + (xi1 + cc))*3;
      dst[0] = v[0]; dst[1] = v[1]; dst[2] = v[2];
    }
    return;
  }

  // ---- crop box n ----
  if (n >= NB) return;
  const float* bst = ws + WS_BOX + (b*NB + n)*8;
  if (bst[5] < 0.5f) return;
  do_crop(img, patch, ws, b, r - PB, n, hasp, yi1, xi1, ph1, phf1,
          pbg1, s_mask, s_ab, s_red);
}

extern "C" void kernel_launch(void* const* d_in, const int* in_sizes, int n_in,
                              void* d_out, int out_size, void* d_ws, size_t ws_size,
                              hipStream_t stream) {
  const float* boxes  = (const float*)d_in[0];
  const float* images = (const float*)d_in[1];
  const float* patch  = (const float*)d_in[2];
  const float* Wsc    = (const float*)d_in[3];
  const float* bsc    = (const float*)d_in[4];
  const float* Wg     = (const float*)d_in[5];
  const float* bgv    = (const float*)d_in[6];
  float* out = (float*)d_out;
  float* ws  = (float*)d_ws;

  setup_k<<<NI*NB + 1, 256, 0, stream>>>(boxes, Wsc, bsc, Wg, bgv, patch, ws);
  step0_k<<<NI*CB + 1 + 2047, 256, 0, stream>>>(out, images, patch, ws);
  for (int n = 1; n <= NB; ++n)
    step_k<<<NI*SB, 256, 0, stream>>>(out, patch, ws, n);
}